// Round 1
// baseline (464.871 us; speedup 1.0000x reference)
//
#include <hip/hip_runtime.h>

// GaborAutoencoder on MI355X (gfx950)
// Pipeline: split X/W into fp16 (hi, lo*4096) pairs -> 4x MFMA GEMM with
// fp16x2 3-pass split precision (fp32-class accuracy) -> Gabor synthesis.
// Weights pre-scaled x256 before split (avoids fp16 denormal hi-parts);
// epilogue: C = (acc_hh + acc_cross/4096)/256 + bias, optional ReLU,
// re-split to fp16 hi/lo for the next layer.

#define SIGNAL_LEN 2048
#define NWAV 32

typedef _Float16 f16x8 __attribute__((ext_vector_type(8)));
typedef _Float16 f16x4 __attribute__((ext_vector_type(4)));
typedef float    f32x4 __attribute__((ext_vector_type(4)));

__device__ __forceinline__ void load16_lds(const _Float16* g, _Float16* l) {
  __builtin_amdgcn_global_load_lds((const __attribute__((address_space(1))) void*)g,
                                   (__attribute__((address_space(3))) void*)l,
                                   16, 0, 0);
}

// ---------------------------------------------------------------------------
// split fp32 -> (hi fp16, lo fp16 = (v - hi)*4096), optional pre-scale
// ---------------------------------------------------------------------------
__global__ void split4(const float4* __restrict__ src, f16x4* __restrict__ dh,
                       f16x4* __restrict__ dl, int n4, float scale) {
  int i = blockIdx.x * 256 + threadIdx.x;
  if (i >= n4) return;
  float4 v = src[i];
  float a[4] = {v.x * scale, v.y * scale, v.z * scale, v.w * scale};
  f16x4 h, l;
#pragma unroll
  for (int j = 0; j < 4; j++) {
    _Float16 hh = (_Float16)a[j];
    h[j] = hh;
    l[j] = (_Float16)((a[j] - (float)hh) * 4096.0f);
  }
  dh[i] = h;
  dl[i] = l;
}

// W4 (160x256) -> padded (256x256), scaled x256, rows >=160 zeroed
__global__ void split_pad_w4(const float* __restrict__ src, f16x4* __restrict__ dh,
                             f16x4* __restrict__ dl) {
  int i = blockIdx.x * 256 + threadIdx.x;  // 16384 threads
  int i4 = i << 2;
  int row = i4 >> 8;
  f16x4 h, l;
#pragma unroll
  for (int j = 0; j < 4; j++) {
    float a = (row < 160) ? src[i4 + j] * 256.0f : 0.0f;
    _Float16 hh = (_Float16)a;
    h[j] = hh;
    l[j] = (_Float16)((a - (float)hh) * 4096.0f);
  }
  dh[i] = h;
  dl[i] = l;
}

__global__ void pad_b4(const float* __restrict__ b, float* __restrict__ bp) {
  int i = threadIdx.x;  // 256 threads
  bp[i] = (i < 160) ? b[i] : 0.0f;
}

// ---------------------------------------------------------------------------
// fp16x2 split-precision GEMM: C[M,N] = A[M,K] * B[N,K]^T  (+bias, relu)
// tile 128(M) x 64(N), BK=32, 256 threads = 4 waves in 2x2, 16x16x32 MFMA
// ---------------------------------------------------------------------------
template <int N, int K, bool RELU, bool SPLIT_OUT>
__global__ void __launch_bounds__(256, 2)
gemm_f16x2(const _Float16* __restrict__ Ah, const _Float16* __restrict__ Al,
           const _Float16* __restrict__ Bh, const _Float16* __restrict__ Bl,
           const float* __restrict__ bias,
           _Float16* __restrict__ Ch, _Float16* __restrict__ Cl,
           float* __restrict__ Cf) {
  __shared__ __align__(16) _Float16 sAh[128 * 32];
  __shared__ __align__(16) _Float16 sAl[128 * 32];
  __shared__ __align__(16) _Float16 sBh[64 * 32];
  __shared__ __align__(16) _Float16 sBl[64 * 32];

  const int tid = threadIdx.x;
  const int lane = tid & 63;
  const int w = tid >> 6;
  const int wm = w >> 1, wn = w & 1;
  const int m0 = blockIdx.y * 128;
  const int n0 = blockIdx.x * 64;

  // staging: chunk ci covers LDS [row=ci>>2][k8=(ci&3)*8], 16B per lane
  const int rowc = tid >> 2;           // 0..63
  const int k8 = (tid & 3) * 8;

  const _Float16* gAh0 = Ah + (size_t)(m0 + rowc) * K + k8;
  const _Float16* gAh1 = gAh0 + (size_t)64 * K;
  const _Float16* gAl0 = Al + (size_t)(m0 + rowc) * K + k8;
  const _Float16* gAl1 = gAl0 + (size_t)64 * K;
  const _Float16* gBh0 = Bh + (size_t)(n0 + rowc) * K + k8;
  const _Float16* gBl0 = Bl + (size_t)(n0 + rowc) * K + k8;

  const int wch = w * 64;  // wave-uniform chunk base
  _Float16* lAh0 = sAh + wch * 8;
  _Float16* lAh1 = sAh + (wch + 256) * 8;
  _Float16* lAl0 = sAl + wch * 8;
  _Float16* lAl1 = sAl + (wch + 256) * 8;
  _Float16* lBh = sBh + wch * 8;
  _Float16* lBl = sBl + wch * 8;

  // MFMA fragment read addresses: A[m=lane&15][k=quad*8+j]
  const int frow = lane & 15;
  const int fko = (lane >> 4) * 8;
  const _Float16* rAh = sAh + (wm * 64 + frow) * 32 + fko;
  const _Float16* rAl = sAl + (wm * 64 + frow) * 32 + fko;
  const _Float16* rBh = sBh + (wn * 32 + frow) * 32 + fko;
  const _Float16* rBl = sBl + (wn * 32 + frow) * 32 + fko;

  f32x4 acc1[4][2], acc2[4][2];
#pragma unroll
  for (int i = 0; i < 4; i++)
#pragma unroll
    for (int j = 0; j < 2; j++) {
      acc1[i][j] = 0.0f;
      acc2[i][j] = 0.0f;
    }

  for (int kt = 0; kt < K; kt += 32) {
    load16_lds(gAh0 + kt, lAh0);
    load16_lds(gAh1 + kt, lAh1);
    load16_lds(gAl0 + kt, lAl0);
    load16_lds(gAl1 + kt, lAl1);
    load16_lds(gBh0 + kt, lBh);
    load16_lds(gBl0 + kt, lBl);
    __syncthreads();

    f16x8 fAh[4], fAl[4], fBh[2], fBl[2];
#pragma unroll
    for (int im = 0; im < 4; im++) {
      fAh[im] = *(const f16x8*)(rAh + im * 512);
      fAl[im] = *(const f16x8*)(rAl + im * 512);
    }
#pragma unroll
    for (int in = 0; in < 2; in++) {
      fBh[in] = *(const f16x8*)(rBh + in * 512);
      fBl[in] = *(const f16x8*)(rBl + in * 512);
    }
#pragma unroll
    for (int im = 0; im < 4; im++) {
#pragma unroll
      for (int in = 0; in < 2; in++) {
        acc1[im][in] = __builtin_amdgcn_mfma_f32_16x16x32_f16(fAh[im], fBh[in], acc1[im][in], 0, 0, 0);
        acc2[im][in] = __builtin_amdgcn_mfma_f32_16x16x32_f16(fAh[im], fBl[in], acc2[im][in], 0, 0, 0);
        acc2[im][in] = __builtin_amdgcn_mfma_f32_16x16x32_f16(fAl[im], fBh[in], acc2[im][in], 0, 0, 0);
      }
    }
    __syncthreads();
  }

  // epilogue: C/D layout col=lane&15, row=quad*4+reg
  const int quad = lane >> 4;
#pragma unroll
  for (int in = 0; in < 2; in++) {
    const int n = n0 + wn * 32 + in * 16 + frow;
    const float bv = bias[n];
#pragma unroll
    for (int im = 0; im < 4; im++) {
#pragma unroll
      for (int r = 0; r < 4; r++) {
        const int m = m0 + wm * 64 + im * 16 + quad * 4 + r;
        float c = (acc1[im][in][r] + acc2[im][in][r] * (1.0f / 4096.0f)) * (1.0f / 256.0f) + bv;
        if (RELU) c = fmaxf(c, 0.0f);
        const size_t off = (size_t)m * N + n;
        if (SPLIT_OUT) {
          _Float16 hh = (_Float16)c;
          Ch[off] = hh;
          Cl[off] = (_Float16)((c - (float)hh) * 4096.0f);
        } else {
          Cf[off] = c;
        }
      }
    }
  }
}

// ---------------------------------------------------------------------------
// Gabor synthesis: one block per batch, 256 threads x 8 t-samples each
// ---------------------------------------------------------------------------
__global__ void __launch_bounds__(256)
synth(const float* __restrict__ P, float* __restrict__ out) {
  __shared__ float sA[NWAV], sT0[NWAV], sF[NWAV], sC[NWAV], sPh[NWAV];
  const int b = blockIdx.x;
  const int tid = threadIdx.x;
  if (tid < NWAV) {
    const float* q = P + (size_t)b * 256 + tid * 5;
    const float L2E = 1.44269504088896340736f;
    float A = q[0], p1 = q[1], p2 = q[2], p3 = q[3], p4 = q[4];
    float s1 = 1.0f / (1.0f + exp2f(-p1 * L2E));
    float s2 = 1.0f / (1.0f + exp2f(-p2 * L2E));
    float s3 = 1.0f / (1.0f + exp2f(-p3 * L2E));
    float sg = s3 * 200.0f + 2.0f;
    sA[tid] = A;
    sT0[tid] = s1 * 2048.0f;
    sF[tid] = s2 * 0.5f;
    sC[tid] = -L2E / (2.0f * sg * sg);          // exp(-dt^2/(2s^2)) = exp2(dt^2*sC)
    sPh[tid] = p4 * 0.15915494309189535f;       // phi in revolutions
  }
  __syncthreads();

  float acc[8];
  float tv[8];
#pragma unroll
  for (int i = 0; i < 8; i++) {
    acc[i] = 0.0f;
    tv[i] = (float)(tid + i * 256);
  }

  for (int wv = 0; wv < NWAV; wv++) {
    const float A = sA[wv], t0 = sT0[wv], fr = sF[wv], cn = sC[wv], ph = sPh[wv];
#pragma unroll
    for (int i = 0; i < 8; i++) {
      float dt = tv[i] - t0;
      float e = exp2f(dt * dt * cn);
      float r = fr * dt + ph;                    // phase in revolutions
      r -= floorf(r);                            // reduce to [0,1)
      float cs = __builtin_amdgcn_cosf(r);       // v_cos_f32: cos(2*pi*r)
      acc[i] += A * e * cs;
    }
  }

  float* o = out + (size_t)b * (2 * SIGNAL_LEN);
#pragma unroll
  for (int i = 0; i < 8; i++) {
    o[tid + i * 256] = acc[i];
    o[SIGNAL_LEN + tid + i * 256] = acc[i];      // both channels identical
  }
}

// ---------------------------------------------------------------------------
extern "C" void kernel_launch(void* const* d_in, const int* in_sizes, int n_in,
                              void* d_out, int out_size, void* d_ws, size_t ws_size,
                              hipStream_t stream) {
  (void)in_sizes; (void)n_in; (void)out_size; (void)ws_size;
  const float* X  = (const float*)d_in[0];
  const float* W1 = (const float*)d_in[1];
  const float* b1 = (const float*)d_in[2];
  const float* W2 = (const float*)d_in[3];
  const float* b2 = (const float*)d_in[4];
  const float* W3 = (const float*)d_in[5];
  const float* b3 = (const float*)d_in[6];
  const float* W4 = (const float*)d_in[7];
  const float* b4 = (const float*)d_in[8];
  float* out = (float*)d_out;

  char* p = (char*)d_ws;
  auto take = [&](size_t bytes) -> char* {
    char* r = p;
    p += (bytes + 255) & ~(size_t)255;
    return r;
  };
  _Float16* Xh  = (_Float16*)take((size_t)4096 * 4096 * 2);
  _Float16* Xl  = (_Float16*)take((size_t)4096 * 4096 * 2);
  _Float16* W1h = (_Float16*)take((size_t)1024 * 4096 * 2);
  _Float16* W1l = (_Float16*)take((size_t)1024 * 4096 * 2);
  _Float16* H1h = (_Float16*)take((size_t)4096 * 1024 * 2);
  _Float16* H1l = (_Float16*)take((size_t)4096 * 1024 * 2);
  _Float16* W2h = (_Float16*)take((size_t)512 * 1024 * 2);
  _Float16* W2l = (_Float16*)take((size_t)512 * 1024 * 2);
  _Float16* H2h = (_Float16*)take((size_t)4096 * 512 * 2);
  _Float16* H2l = (_Float16*)take((size_t)4096 * 512 * 2);
  _Float16* W3h = (_Float16*)take((size_t)256 * 512 * 2);
  _Float16* W3l = (_Float16*)take((size_t)256 * 512 * 2);
  _Float16* H3h = (_Float16*)take((size_t)4096 * 256 * 2);
  _Float16* H3l = (_Float16*)take((size_t)4096 * 256 * 2);
  _Float16* W4h = (_Float16*)take((size_t)256 * 256 * 2);
  _Float16* W4l = (_Float16*)take((size_t)256 * 256 * 2);
  float*    b4p = (float*)take(256 * 4);
  float*    Pp  = (float*)take((size_t)4096 * 256 * 4);

  // input splits (weights pre-scaled x256)
  split4<<<16384, 256, 0, stream>>>((const float4*)X, (f16x4*)Xh, (f16x4*)Xl, 4194304, 1.0f);
  split4<<<4096, 256, 0, stream>>>((const float4*)W1, (f16x4*)W1h, (f16x4*)W1l, 1048576, 256.0f);
  split4<<<512, 256, 0, stream>>>((const float4*)W2, (f16x4*)W2h, (f16x4*)W2l, 131072, 256.0f);
  split4<<<128, 256, 0, stream>>>((const float4*)W3, (f16x4*)W3h, (f16x4*)W3l, 32768, 256.0f);
  split_pad_w4<<<64, 256, 0, stream>>>(W4, (f16x4*)W4h, (f16x4*)W4l);
  pad_b4<<<1, 256, 0, stream>>>(b4, b4p);

  // encoder
  gemm_f16x2<1024, 4096, true, true><<<dim3(16, 32), 256, 0, stream>>>(
      Xh, Xl, W1h, W1l, b1, H1h, H1l, nullptr);
  gemm_f16x2<512, 1024, true, true><<<dim3(8, 32), 256, 0, stream>>>(
      H1h, H1l, W2h, W2l, b2, H2h, H2l, nullptr);
  gemm_f16x2<256, 512, true, true><<<dim3(4, 32), 256, 0, stream>>>(
      H2h, H2l, W3h, W3l, b3, H3h, H3l, nullptr);
  gemm_f16x2<256, 256, false, false><<<dim3(4, 32), 256, 0, stream>>>(
      H3h, H3l, W4h, W4l, b4p, nullptr, nullptr, Pp);

  // synthesis
  synth<<<4096, 256, 0, stream>>>(Pp, out);
}